// Round 2
// baseline (1019.341 us; speedup 1.0000x reference)
//
#include <hip/hip_runtime.h>

// Binary conv2d: x (8,16,1024,1024) fp32, w (16,16,3,3) in {0,1} decoded to
// +/-1, stride (2,2), pad (1,1) zeros => out (8,16,512,512) fp32.
//
// R4: 2x2-output register blocking (R3) + 2-deep ping-pong prefetch across
// the ci loop. R3 (742->732.6 us total) showed a 2.4x VMEM-instruction cut
// is nearly free => binconv is not load-issue-bound. Hypothesis: each ci
// iteration serializes addr -> 10 loads -> vmcnt wait -> 576 FMAs, and
// 4 near-lockstep waves/SIMD don't hide the ~200-900 cyc wait. Fix: issue
// the NEXT channel's 5 aligned float4 window rows before the current
// channel's 576-FMA block (loads fly under ~1152 cyc of FMA issue). The 5
// left-column scalars stay just-in-time (L1 hits: their lines were pulled
// by neighbor lanes' float4s) and are consumed LAST (kx={1,2} taps first,
// kx=0 taps last). Budget: 2x20 window + 64 acc + 5 offs ~= 120 VGPR
// under the __launch_bounds__(256,4) 128-cap.

#define IN_H   1024
#define IN_W   1024
#define OUT_H  512
#define OUT_W  512
#define C_IN   16
#define C_OUT  16

// decode {0,1}->{+1,-1}, transpose OIHW -> [ci][tap][co] (co contiguous
// so per-(ci,tap) weights are an s_load_dwordx16 candidate).
__global__ void decode_weights(const float* __restrict__ w,
                               float* __restrict__ wdec) {
    int i = blockIdx.x * blockDim.x + threadIdx.x;   // 16*9*16 = 2304
    if (i >= C_IN * 9 * C_OUT) return;
    int co  = i & 15;
    int t   = i >> 4;        // ci*9 + tap
    int tap = t % 9;
    int ci  = t / 9;
    float v = w[(co * C_IN + ci) * 9 + tap];
    wdec[i] = (v == 1.0f) ? 1.0f : -1.0f;
}

__global__ __launch_bounds__(256, 4)
void binconv(const float* __restrict__ x,
             const float* __restrict__ wdec,
             float* __restrict__ out) {
    const int tx = threadIdx.x;                 // 0..63
    const int ty = threadIdx.y;                 // 0..3
    const int OW = blockIdx.x * 64 + tx;        // output col-PAIR index 0..255
    const int OH = blockIdx.y * 4 + ty;         // output row-PAIR index 0..255
    const int n  = blockIdx.z;                  // 0..7

    const float* xn = x + (size_t)n * C_IN * IN_H * IN_W;
    // 2x2 outputs at (2OH..2OH+1, 2OW..2OW+1) need input rows 4OH-1..4OH+3,
    // cols 4OW-1..4OW+3. Only row -1 (OH==0) / col -1 (OW==0) can be OOB;
    // bottom/right land exactly at 1023. Clamp addr, select 0 after.
    const int gx0 = 4 * OW - 1;   // input col of kx=0, left output
    const int gy0 = 4 * OH - 1;   // input row of ky=0, top output

    const bool colm_ok = (OW > 0);
    const bool row0_ok = (OH > 0);

    // element offsets of the aligned float4 (cols 4OW..4OW+3), 5 rows,
    // row 0 clamped; scalar left-col is roff[r]+dsm (dsm=0 when clamped).
    int roff[5];
#pragma unroll
    for (int r = 0; r < 5; ++r) {
        const int gy = (r == 0) ? (row0_ok ? gy0 : 0) : (gy0 + r);
        roff[r] = gy * IN_W + (gx0 + 1);
    }
    const int dsm = colm_ok ? -1 : 0;

    float a00[C_OUT], a01[C_OUT], a10[C_OUT], a11[C_OUT];
#pragma unroll
    for (int co = 0; co < C_OUT; ++co) {
        a00[co] = 0.0f; a01[co] = 0.0f; a10[co] = 0.0f; a11[co] = 0.0f;
    }

    // FMA block for one channel: f4[] already in regs (prefetched), the 5
    // left-col scalars are loaded here (L1 hits) and consumed last.
    auto compute = [&](const float4 (&f4)[5], const float* xc, int ci) {
        float sm[5];
#pragma unroll
        for (int r = 0; r < 5; ++r) sm[r] = xc[roff[r] + dsm];

        float xv[5][5];
#pragma unroll
        for (int r = 0; r < 5; ++r) {
            const bool rok = (r == 0) ? row0_ok : true;   // static for r>=1
            xv[r][0] = (rok && colm_ok) ? sm[r] : 0.0f;
            xv[r][1] = rok ? f4[r].x : 0.0f;
            xv[r][2] = rok ? f4[r].y : 0.0f;
            xv[r][3] = rok ? f4[r].z : 0.0f;
            xv[r][4] = rok ? f4[r].w : 0.0f;
        }

        const float* wc = wdec + ci * 9 * C_OUT;
        // pass 1: kx = 1,2 (float4-only data), 384 FMAs
#pragma unroll
        for (int ky = 0; ky < 3; ++ky) {
#pragma unroll
            for (int kx = 1; kx < 3; ++kx) {
                const int t = ky * 3 + kx;
                const float x00 = xv[ky][kx],     x01 = xv[ky][kx + 2];
                const float x10 = xv[ky + 2][kx], x11 = xv[ky + 2][kx + 2];
#pragma unroll
                for (int co = 0; co < C_OUT; ++co) {
                    const float w = wc[t * C_OUT + co];
                    a00[co] = fmaf(w, x00, a00[co]);
                    a01[co] = fmaf(w, x01, a01[co]);
                    a10[co] = fmaf(w, x10, a10[co]);
                    a11[co] = fmaf(w, x11, a11[co]);
                }
            }
        }
        // pass 2: kx = 0 (needs the scalar column), 192 FMAs
#pragma unroll
        for (int ky = 0; ky < 3; ++ky) {
            const int t = ky * 3;
            const float x00 = xv[ky][0],     x01 = xv[ky][2];
            const float x10 = xv[ky + 2][0], x11 = xv[ky + 2][2];
#pragma unroll
            for (int co = 0; co < C_OUT; ++co) {
                const float w = wc[t * C_OUT + co];
                a00[co] = fmaf(w, x00, a00[co]);
                a01[co] = fmaf(w, x01, a01[co]);
                a10[co] = fmaf(w, x10, a10[co]);
                a11[co] = fmaf(w, x11, a11[co]);
            }
        }
    };

    const size_t cstride = (size_t)IN_H * IN_W;

    // prologue: window for ci=0
    float4 fA[5], fB[5];
    {
        const float* xc0 = xn;
#pragma unroll
        for (int r = 0; r < 5; ++r) fA[r] = *(const float4*)(xc0 + roff[r]);
    }

    // ping-pong: prefetch ci+1's float4 rows, then run ci's FMA block.
    for (int c2 = 0; c2 < C_IN / 2; ++c2) {
        const int ciA = 2 * c2, ciB = ciA + 1;
        const float* xcA = xn + (size_t)ciA * cstride;
        const float* xcB = xn + (size_t)ciB * cstride;
        const int ciN = (ciB + 1 < C_IN) ? (ciB + 1) : (C_IN - 1);  // clamp: re-read ci=15 (L1 hit)
        const float* xcN = xn + (size_t)ciN * cstride;

#pragma unroll
        for (int r = 0; r < 5; ++r) fB[r] = *(const float4*)(xcB + roff[r]);
        compute(fA, xcA, ciA);

#pragma unroll
        for (int r = 0; r < 5; ++r) fA[r] = *(const float4*)(xcN + roff[r]);
        compute(fB, xcB, ciB);
    }

    // 2x2 patch -> two float2 stores per co; lanes write 8B each,
    // contiguous across the wave (512B/row/wave).
    const int oh = 2 * OH, ow = 2 * OW;
    float* op = out + (size_t)n * C_OUT * OUT_H * OUT_W
                    + (size_t)oh * OUT_W + ow;
#pragma unroll
    for (int co = 0; co < C_OUT; ++co) {
        float* p = op + (size_t)co * OUT_H * OUT_W;
        *(float2*)(p)         = make_float2(a00[co], a01[co]);
        *(float2*)(p + OUT_W) = make_float2(a10[co], a11[co]);
    }
}

extern "C" void kernel_launch(void* const* d_in, const int* in_sizes, int n_in,
                              void* d_out, int out_size, void* d_ws, size_t ws_size,
                              hipStream_t stream) {
    const float* x = (const float*)d_in[0];
    const float* w = (const float*)d_in[1];
    float* out = (float*)d_out;
    float* wdec = (float*)d_ws;   // 2304 floats = 9216 B

    decode_weights<<<dim3((C_IN * 9 * C_OUT + 255) / 256), dim3(256), 0, stream>>>(w, wdec);

    // block (64,4): 64 col-pairs x 4 row-pairs = 128x8 output tile.
    dim3 block(64, 4, 1);
    dim3 grid(OUT_W / 128, OUT_H / 8, 8);   // (4, 64, 8)
    binconv<<<grid, block, 0, stream>>>(x, wdec, out);
}